// Round 2
// baseline (205.160 us; speedup 1.0000x reference)
//
#include <hip/hip_runtime.h>

#define BATCH 32
#define H 512
#define W 512
#define PAD 4
#define WIN 9
#define SEG 32                      // output rows per block
#define TILE 256                    // columns per block
#define HCOLS (TILE + 2 * PAD)      // 264 staged columns (incl. halo)
#define NSTEP (SEG + WIN - 1)       // 40 row-steps
// final scalar = sum over pixels of ((1-cc1)+(1-cc2)) * 0.5 / (B*H*W)
#define SCALE (0.5f / 8388608.0f)

__global__ __launch_bounds__(256, 4) void ncc_loss_kernel(
    const float* __restrict__ g1, const float* __restrict__ g2,
    const float* __restrict__ gf, float* __restrict__ out)
{
    // double-buffered staged rows: [buf][image][column]
    __shared__ float sm[2][3][HCOLS];

    const int t  = threadIdx.x;
    const int x0 = blockIdx.x * TILE;
    const int y0 = blockIdx.y * SEG;
    const int b  = blockIdx.z;
    const size_t base = (size_t)b * (H * W);
    const float* I1 = g1 + base;
    const float* I2 = g2 + base;
    const float* F  = gf + base;

    // 9-deep register ring of horizontal 9-sums (ring idx is compile-time ph)
    float r1[WIN], r2[WIN], rf[WIN], r11[WIN], r22[WIN], rff[WIN], r1f[WIN], r2f[WIN];
#pragma unroll
    for (int i = 0; i < WIN; ++i) {
        r1[i]=0.f; r2[i]=0.f; rf[i]=0.f; r11[i]=0.f;
        r22[i]=0.f; rff[i]=0.f; r1f[i]=0.f; r2f[i]=0.f;
    }
    float v1=0.f,v2=0.f,vf=0.f,v11=0.f,v22=0.f,vff=0.f,v1f=0.f,v2f=0.f;
    float lsum = 0.f;
    const float inv_n = 1.0f / 81.0f;

    // one row-step; ph must be a compile-time constant at each call site
    auto do_step = [&](int step, int ph) {
        const int buf = step & 1;
        const int yr  = y0 - PAD + step;           // incoming raw row
        const bool rowok = (yr >= 0 && yr < H);    // wave-uniform
        const size_t roff = (size_t)yr * W;

        // ---- stage row into LDS (zero-filled padding) ----
        {
            float a0=0.f, c0=0.f, f0=0.f;
            const int cx = x0 - PAD + t;
            if (rowok && (unsigned)cx < (unsigned)W) {
                a0 = I1[roff + cx]; c0 = I2[roff + cx]; f0 = F[roff + cx];
            }
            sm[buf][0][t] = a0; sm[buf][1][t] = c0; sm[buf][2][t] = f0;
        }
        if (t < HCOLS - TILE) {                    // 8 halo columns
            float a1=0.f, c1=0.f, f1=0.f;
            const int cx = x0 - PAD + TILE + t;
            if (rowok && (unsigned)cx < (unsigned)W) {
                a1 = I1[roff + cx]; c1 = I2[roff + cx]; f1 = F[roff + cx];
            }
            sm[buf][0][TILE + t] = a1; sm[buf][1][TILE + t] = c1; sm[buf][2][TILE + t] = f1;
        }
        __syncthreads();   // single barrier/step; double-buffer orders the WAR

        // ---- horizontal 9-tap sums of the 8 quantities from LDS ----
        float s1=0.f,s2=0.f,sf=0.f,s11=0.f,s22=0.f,sff=0.f,s1f=0.f,s2f=0.f;
#pragma unroll
        for (int k = 0; k < WIN; ++k) {
            const float a = sm[buf][0][t + k];
            const float c = sm[buf][1][t + k];
            const float f = sm[buf][2][t + k];
            s1 += a; s2 += c; sf += f;
            s11 = fmaf(a, a, s11);
            s22 = fmaf(c, c, s22);
            sff = fmaf(f, f, sff);
            s1f = fmaf(a, f, s1f);
            s2f = fmaf(c, f, s2f);
        }

        // ---- vertical sliding window via register ring ----
        v1  += s1  - r1[ph];  r1[ph]  = s1;
        v2  += s2  - r2[ph];  r2[ph]  = s2;
        vf  += sf  - rf[ph];  rf[ph]  = sf;
        v11 += s11 - r11[ph]; r11[ph] = s11;
        v22 += s22 - r22[ph]; r22[ph] = s22;
        vff += sff - rff[ph]; rff[ph] = sff;
        v1f += s1f - r1f[ph]; r1f[ph] = s1f;
        v2f += s2f - r2f[ph]; r2f[ph] = s2f;

        if (step >= WIN - 1) {                     // emit output row yr - PAD
            const float cross1 = v1f - v1 * vf * inv_n;
            const float var1   = v11 - v1 * v1 * inv_n;
            const float varf   = vff - vf * vf * inv_n;
            const float cross2 = v2f - v2 * vf * inv_n;
            const float var2   = v22 - v2 * v2 * inv_n;
            const float cc1 = cross1 * cross1 / (var1 * varf + 1e-5f);
            const float cc2 = cross2 * cross2 / (var2 * varf + 1e-5f);
            lsum += (2.0f - cc1 - cc2);
        }
    };

    // 40 steps = 4 x 9 phases + 4 tail phases (36 % 9 == 0, so ring idx == ph)
    for (int os = 0; os < NSTEP / WIN; ++os) {
#pragma unroll
        for (int ph = 0; ph < WIN; ++ph) do_step(os * WIN + ph, ph);
    }
#pragma unroll
    for (int ph = 0; ph < NSTEP % WIN; ++ph) do_step((NSTEP / WIN) * WIN + ph, ph);

    // block reduction: wave shuffle -> LDS -> one atomic per block
#pragma unroll
    for (int off = 32; off > 0; off >>= 1)
        lsum += __shfl_down(lsum, off);
    __shared__ float wsum[4];
    const int lane = threadIdx.x & 63;
    const int wid  = threadIdx.x >> 6;
    if (lane == 0) wsum[wid] = lsum;
    __syncthreads();
    if (threadIdx.x == 0) {
        atomicAdd(out, (wsum[0] + wsum[1] + wsum[2] + wsum[3]) * SCALE);
    }
}

extern "C" void kernel_launch(void* const* d_in, const int* in_sizes, int n_in,
                              void* d_out, int out_size, void* d_ws, size_t ws_size,
                              hipStream_t stream) {
    const float* img1 = (const float*)d_in[0];
    const float* img2 = (const float*)d_in[1];
    const float* fimg = (const float*)d_in[2];
    float* out = (float*)d_out;

    hipMemsetAsync(out, 0, sizeof(float), stream);  // d_out is re-poisoned each call

    dim3 grid(W / TILE, H / SEG, BATCH);   // (2, 16, 32) = 1024 blocks
    ncc_loss_kernel<<<grid, dim3(256), 0, stream>>>(img1, img2, fimg, out);
}